// Round 6
// baseline (80.804 us; speedup 1.0000x reference)
//
#include <hip/hip_runtime.h>

// Inverse DTCWT (biort legall) — zero-LDS, shuffle-halo, single-wave blocks.
// Lane c owns subband cols {2c,2c+1} (float2) and Yl/output cols 4c..4c+3.
// Halo cols come from __shfl_up/__shfl_down; c2q combine in-register;
// quad-level column reflection handled by edge-lane pair swaps.
// A/B register rotation, 1-stage load-ahead, no barriers.

#define Hh 256
#define Ww 256
#define W2 128
#define SBsz (128 * 128)
#define TH 16
#define NST (TH / 2 + 2)   // 10 stages: row-pairs ip0-1 .. ip0+8 (reflected)

struct Raw {
    float2 b[3][4];   // [pair][comp: s1r,s2r,s1i,s2i] at subband cols 2c,2c+1
    float4 y0, y1;    // Yl rows 2ip, 2ip+1, cols 4c..4c+3
};

__global__ __launch_bounds__(64, 3) void dtcwt_inv(
    const float* __restrict__ Yl,
    const float* __restrict__ Yhr,
    const float* __restrict__ Yhi,
    const float* __restrict__ g0o,
    const float* __restrict__ g1o,
    float* __restrict__ out)
{
    const float SC = 0.70710678118654752440f;  // sqrt(0.5)
    const int c = threadIdx.x;            // 0..63
    const int plane = blockIdx.x;
    const int i0 = blockIdx.y * TH;
    const int ip0 = i0 >> 1;

    const float* yl  = Yl  + (size_t)plane * (Hh * Ww);
    const float* phr = Yhr + (size_t)plane * 6 * SBsz;
    const float* phi = Yhi + (size_t)plane * 6 * SBsz;
    float* outp = out + (size_t)plane * (Hh * Ww);

    float g0[3], g1[5], g0s[3], g1s[5];
#pragma unroll
    for (int t = 0; t < 3; ++t) { g0[t] = g0o[t]; g0s[t] = g0[t] * SC; }
#pragma unroll
    for (int t = 0; t < 5; ++t) { g1[t] = g1o[t]; g1s[t] = g1[t] * SC; }

    // pair p -> subband indices (a1, a2): lh=(0,5), hl=(2,3), hh=(1,4)
    constexpr int PB1[3] = {0, 2, 1};
    constexpr int PB2[3] = {5, 3, 4};

    auto loadStage = [&](int s, Raw& R) {
        int sc_ = s < NST ? s : NST - 1;
        int v = ip0 - 1 + sc_;
        int ip = v < 0 ? 0 : (v > 127 ? 127 : v);
        const int off = ip * W2 + 2 * c;
#pragma unroll
        for (int p = 0; p < 3; ++p) {
            R.b[p][0] = *(const float2*)(phr + PB1[p] * SBsz + off);
            R.b[p][1] = *(const float2*)(phr + PB2[p] * SBsz + off);
            R.b[p][2] = *(const float2*)(phi + PB1[p] * SBsz + off);
            R.b[p][3] = *(const float2*)(phi + PB2[p] * SBsz + off);
        }
        R.y0 = *(const float4*)(yl + (size_t)(2 * ip) * Ww + 4 * c);
        R.y1 = *(const float4*)(yl + (size_t)(2 * ip + 1) * Ww + 4 * c);
    };

    float w1[4][4], w2[4][4];  // per-col column-filter windows

    auto computeStage = [&](int s, const Raw& R) {
        float y10[4], y11[4], y20[4], y21[4];
#pragma unroll
        for (int dx = 0; dx < 4; ++dx) { y10[dx]=0.f; y11[dx]=0.f; y20[dx]=0.f; y21[dx]=0.f; }

#pragma unroll
        for (int p = 0; p < 3; ++p) {
            const float2 a = R.b[p][0], b = R.b[p][1];
            const float2 ci = R.b[p][2], di = R.b[p][3];
            float La = __shfl_up(a.y, 1);  if (c == 0)  La = a.x;
            float Lb = __shfl_up(b.y, 1);  if (c == 0)  Lb = b.x;
            float Lc = __shfl_up(ci.y, 1); if (c == 0)  Lc = ci.x;
            float Ld = __shfl_up(di.y, 1); if (c == 0)  Ld = di.x;
            float Ra = __shfl_down(a.x, 1);  if (c == 63) Ra = a.y;
            float Rb = __shfl_down(b.x, 1);  if (c == 63) Rb = b.y;
            float Rc = __shfl_down(ci.x, 1); if (c == 63) Rc = ci.y;
            float Rd = __shfl_down(di.x, 1); if (c == 63) Rd = di.y;

            // quad windows: cols 4c-2 .. 4c+5, parity 0 (q0w) and 1 (q1w)
            float q0w[8], q1w[8];
            {   // m=0 (L), m=1 (.x), m=2 (.y), m=3 (R)
                float a1r[4] = {La, a.x, a.y, Ra};
                float a2r[4] = {Lb, b.x, b.y, Rb};
                float a1i[4] = {Lc, ci.x, ci.y, Rc};
                float a2i[4] = {Ld, di.x, di.y, Rd};
#pragma unroll
                for (int m = 0; m < 4; ++m) {
                    q0w[2*m]   = a1r[m] + a2r[m];   // Sr
                    q0w[2*m+1] = a1i[m] + a2i[m];   // Si
                    q1w[2*m]   = a1i[m] - a2i[m];   // Di
                    q1w[2*m+1] = a2r[m] - a1r[m];   // Dr
                }
            }
            // quad-level column reflection at the image edges swaps pair order
            if (c == 0) {
                float t0 = q0w[0]; q0w[0] = q0w[1]; q0w[1] = t0;
                float t1 = q1w[0]; q1w[0] = q1w[1]; q1w[1] = t1;
            }
            if (c == 63) {
                float t0 = q0w[6]; q0w[6] = q0w[7]; q0w[7] = t0;
                float t1 = q1w[6]; q1w[6] = q1w[7]; q1w[7] = t1;
            }
#pragma unroll
            for (int dx = 0; dx < 4; ++dx) {
                if (p == 1) {        // hl quad -> y1, 5-tap g1 (SC folded)
#pragma unroll
                    for (int t = 0; t < 5; ++t) {
                        y10[dx] += g1s[t] * q0w[dx + t];
                        y11[dx] += g1s[t] * q1w[dx + t];
                    }
                } else if (p == 0) { // lh quad -> y2, 3-tap g0 (SC folded)
#pragma unroll
                    for (int t = 0; t < 3; ++t) {
                        y20[dx] += g0s[t] * q0w[dx + 1 + t];
                        y21[dx] += g0s[t] * q1w[dx + 1 + t];
                    }
                } else {             // hh quad -> y2, 5-tap g1 (SC folded)
#pragma unroll
                    for (int t = 0; t < 5; ++t) {
                        y20[dx] += g1s[t] * q0w[dx + t];
                        y21[dx] += g1s[t] * q1w[dx + t];
                    }
                }
            }
        }

        // Yl row filter (plain g0), windows cols 4c-1 .. 4c+4
        {
            float yw0[6], yw1[6];
            yw0[0] = __shfl_up(R.y0.w, 1);  if (c == 0)  yw0[0] = R.y0.x;
            yw1[0] = __shfl_up(R.y1.w, 1);  if (c == 0)  yw1[0] = R.y1.x;
            yw0[5] = __shfl_down(R.y0.x, 1); if (c == 63) yw0[5] = R.y0.w;
            yw1[5] = __shfl_down(R.y1.x, 1); if (c == 63) yw1[5] = R.y1.w;
            yw0[1] = R.y0.x; yw0[2] = R.y0.y; yw0[3] = R.y0.z; yw0[4] = R.y0.w;
            yw1[1] = R.y1.x; yw1[2] = R.y1.y; yw1[3] = R.y1.z; yw1[4] = R.y1.w;
#pragma unroll
            for (int dx = 0; dx < 4; ++dx) {
#pragma unroll
                for (int t = 0; t < 3; ++t) {
                    y10[dx] += g0[t] * yw0[dx + t];
                    y11[dx] += g0[t] * yw1[dx + t];
                }
            }
        }

        // vertical reflection order + column filter sliding window
        int v = ip0 - 1 + s;
        bool rev = (v < 0) || (v > 127);
        float o0[4], o1[4];
#pragma unroll
        for (int dx = 0; dx < 4; ++dx) {
            float A1 = rev ? y11[dx] : y10[dx];
            float B1 = rev ? y10[dx] : y11[dx];
            float A2 = rev ? y21[dx] : y20[dx];
            float B2 = rev ? y20[dx] : y21[dx];
            if (s == 0) {
                w1[dx][0] = A1; w1[dx][1] = B1; w2[dx][0] = A2; w2[dx][1] = B2;
            } else if (s == 1) {
                w1[dx][2] = A1; w1[dx][3] = B1; w2[dx][2] = A2; w2[dx][3] = B2;
            } else {
                o0[dx] = g0[0]*w1[dx][1] + g0[1]*w1[dx][2] + g0[2]*w1[dx][3]
                       + g1[0]*w2[dx][0] + g1[1]*w2[dx][1] + g1[2]*w2[dx][2]
                       + g1[3]*w2[dx][3] + g1[4]*A2;
                o1[dx] = g0[0]*w1[dx][2] + g0[1]*w1[dx][3] + g0[2]*A1
                       + g1[0]*w2[dx][1] + g1[1]*w2[dx][2] + g1[2]*w2[dx][3]
                       + g1[3]*A2 + g1[4]*B2;
                w1[dx][0] = w1[dx][2]; w1[dx][1] = w1[dx][3]; w1[dx][2] = A1; w1[dx][3] = B1;
                w2[dx][0] = w2[dx][2]; w2[dx][1] = w2[dx][3]; w2[dx][2] = A2; w2[dx][3] = B2;
            }
        }
        if (s >= 2) {
            const int r0 = i0 + 2 * (s - 2);
            *(float4*)(outp + (size_t)r0 * Ww + 4 * c) =
                make_float4(o0[0], o0[1], o0[2], o0[3]);
            *(float4*)(outp + (size_t)(r0 + 1) * Ww + 4 * c) =
                make_float4(o1[0], o1[1], o1[2], o1[3]);
        }
    };

    Raw A, B;
    loadStage(0, A);
#pragma unroll
    for (int sb = 0; sb < NST; sb += 2) {
        loadStage(sb + 1, B);     // issue next stage's loads before computing
        computeStage(sb, A);
        loadStage(sb + 2, A);
        computeStage(sb + 1, B);
    }
}

extern "C" void kernel_launch(void* const* d_in, const int* in_sizes, int n_in,
                              void* d_out, int out_size, void* d_ws, size_t ws_size,
                              hipStream_t stream) {
    const float* Yl  = (const float*)d_in[0];
    const float* Yhr = (const float*)d_in[1];
    const float* Yhi = (const float*)d_in[2];
    const float* g0o = (const float*)d_in[3];
    const float* g1o = (const float*)d_in[4];
    float* outp = (float*)d_out;
    dim3 grid(256, Hh / TH);   // 256 planes x 16 row tiles, 1 wave per block
    dim3 block(64);
    hipLaunchKernelGGL(dtcwt_inv, grid, block, 0, stream,
                       Yl, Yhr, Yhi, g0o, g1o, outp);
}

// Round 8
// 75.722 us; speedup vs baseline: 1.0671x; 1.0671x over previous
//
#include <hip/hip_runtime.h>

// Inverse DTCWT (biort legall) — fused, global_load_lds ring-4 pipeline with
// counted vmcnt (issue-first ladder: issue(s+2); WAIT(8); BAR; compute(s)).
// 128-thread blocks (2 waves), TH=32. Stage buffer (8KB): 12 subband rows
// [q*128+col] (q=0..5 Yhr, 6..11 Yhi) + 2 Yl rows at 1536/1792. Each wave
// issues 4 global_load_lds_dwordx4 per stage (LDS dest linear). Compute:
// 2 output cols/thread, c2q in-register, column filter in register window.

#define Hh 256
#define Ww 256
#define W2 128
#define SBsz (128 * 128)
#define TH 32
#define NST (TH / 2 + 2)   // 18 stages: row-pairs ip0-1 .. ip0+16 (clamped)
#define YOFF 1536

__device__ __forceinline__ int reflect_idx(int m, int N) {
    if (m < 0) m = -m - 1;
    if (m >= N) m = 2 * N - 1 - m;
    return m;
}

#define WAIT(n) asm volatile("s_waitcnt vmcnt(" #n ")" ::: "memory")
#define LGKM0() asm volatile("s_waitcnt lgkmcnt(0)" ::: "memory")
#define BAR() __builtin_amdgcn_s_barrier()

__global__ __launch_bounds__(128) void dtcwt_inv(
    const float* __restrict__ Yl,
    const float* __restrict__ Yhr,
    const float* __restrict__ Yhi,
    const float* __restrict__ g0o,
    const float* __restrict__ g1o,
    float* __restrict__ out)
{
    const float SC = 0.70710678118654752440f;  // sqrt(0.5)
    __shared__ float ring[4][2048];

    const int c = threadIdx.x;        // 0..127: output cols 2c, 2c+1
    const int plane = blockIdx.x;
    const int i0 = blockIdx.y * TH;
    const int ip0 = i0 >> 1;

    const float* yl  = Yl  + (size_t)plane * (Hh * Ww);
    const float* phr = Yhr + (size_t)plane * 6 * SBsz;
    const float* phi = Yhi + (size_t)plane * 6 * SBsz;
    float* outp = out + (size_t)plane * (Hh * Ww);

    float g0[3], g1[5];
#pragma unroll
    for (int t = 0; t < 3; ++t) g0[t] = g0o[t];
#pragma unroll
    for (int t = 0; t < 5; ++t) g1[t] = g1o[t];

    // Quad-col tables: qcols 2c-2 .. 2c+3 -> subband col (even slots) + parity.
    int jcs[3], vq[6];
#pragma unroll
    for (int k = 0; k < 6; ++k) {
        int qq = reflect_idx(2 * c - 2 + k, Ww);
        if ((k & 1) == 0) jcs[k >> 1] = qq >> 1;
        vq[k] = qq & 1;
    }
    const int ylc0 = reflect_idx(2 * c - 1, Ww);
    const int ylc3 = reflect_idx(2 * c + 2, Ww);

    // ---- async staging: wave w covers chunks w*4..w*4+3 (chunk = 256 floats)
    const int wv = c >> 6, lane = c & 63;
    auto issue = [&](int s) {
        int v = ip0 - 1 + s;
        int ip = v < 0 ? 0 : (v > 127 ? 127 : v);
        float* B = ring[s & 3];
#pragma unroll
        for (int rep = 0; rep < 4; ++rep) {
            const int chunk = wv * 4 + rep;
            const float* src;
            if (chunk < 6) {                   // 2 subband rows per chunk
                int q = 2 * chunk + (lane >> 5);
                const float* bq = (q < 6) ? phr + (size_t)q * SBsz
                                          : phi + (size_t)(q - 6) * SBsz;
                src = bq + ip * W2 + ((lane & 31) << 2);
            } else {                           // Yl rows 2ip, 2ip+1
                src = yl + (size_t)(2 * ip + (chunk - 6)) * Ww + (lane << 2);
            }
            __builtin_amdgcn_global_load_lds(
                (const __attribute__((address_space(1))) void*)src,
                (__attribute__((address_space(3))) void*)(B + chunk * 256),
                16, 0, 0);
        }
    };

    float w1a[4], w1b[4], w2a[4], w2b[4];  // column windows, cols 2c / 2c+1
    const float SCg1[5] = {g1[0]*SC, g1[1]*SC, g1[2]*SC, g1[3]*SC, g1[4]*SC};
    const float SCg0[3] = {g0[0]*SC, g0[1]*SC, g0[2]*SC};

    auto computeStage = [&](int s) {
        const float* B = ring[s & 3];
        // Yl row filter, windows cols 2c-1 .. 2c+2
        float ya0 = B[YOFF + ylc0],       ya1 = B[YOFF + 2*c];
        float ya2 = B[YOFF + 2*c + 1],    ya3 = B[YOFF + ylc3];
        float yb0 = B[YOFF + 256 + ylc0], yb1 = B[YOFF + 256 + 2*c];
        float yb2 = B[YOFF + 256 + 2*c+1],yb3 = B[YOFF + 256 + ylc3];
        float y1_00 = g0[0]*ya0 + g0[1]*ya1 + g0[2]*ya2;
        float y1_01 = g0[0]*ya1 + g0[1]*ya2 + g0[2]*ya3;
        float y1_10 = g0[0]*yb0 + g0[1]*yb1 + g0[2]*yb2;
        float y1_11 = g0[0]*yb1 + g0[1]*yb2 + g0[2]*yb3;
        float y2_00 = 0.f, y2_01 = 0.f, y2_10 = 0.f, y2_11 = 0.f;
#pragma unroll
        for (int m = 0; m < 3; ++m) {
            const int col = jcs[m];
            float lr1 = B[col],           lr2 = B[640 + col];        // lh 0,5
            float hr1 = B[256 + col],     hr2 = B[384 + col];        // hl 2,3
            float er1 = B[128 + col],     er2 = B[512 + col];        // hh 1,4
            float li1 = B[768 + col],       li2 = B[768 + 640 + col];
            float hi1 = B[768 + 256 + col], hi2 = B[768 + 384 + col];
            float ei1 = B[768 + 128 + col], ei2 = B[768 + 512 + col];
            float lSr = lr1 + lr2, lSi = li1 + li2, lDi = li1 - li2, lDr = lr2 - lr1;
            float hSr = hr1 + hr2, hSi = hi1 + hi2, hDi = hi1 - hi2, hDr = hr2 - hr1;
            float eSr = er1 + er2, eSi = ei1 + ei2, eDi = ei1 - ei2, eDr = er2 - er1;
#pragma unroll
            for (int kk = 0; kk < 2; ++kk) {
                const int k = 2 * m + kk;
                const int vv = vq[k];
                float qh0 = vv ? hSi : hSr, qh1 = vv ? hDr : hDi;
                float qe0 = vv ? eSi : eSr, qe1 = vv ? eDr : eDi;
                float ql0 = vv ? lSi : lSr, ql1 = vv ? lDr : lDi;
                if (k <= 4) {
                    y1_00 += SCg1[k] * qh0; y1_10 += SCg1[k] * qh1;
                    y2_00 += SCg1[k] * qe0; y2_10 += SCg1[k] * qe1;
                }
                if (k >= 1) {
                    y1_01 += SCg1[k - 1] * qh0; y1_11 += SCg1[k - 1] * qh1;
                    y2_01 += SCg1[k - 1] * qe0; y2_11 += SCg1[k - 1] * qe1;
                }
                if (k >= 1 && k <= 3) {
                    y2_00 += SCg0[k - 1] * ql0; y2_10 += SCg0[k - 1] * ql1;
                }
                if (k >= 2 && k <= 4) {
                    y2_01 += SCg0[k - 2] * ql0; y2_11 += SCg0[k - 2] * ql1;
                }
            }
        }
        // vertical reflection order + column-filter sliding window
        int v = ip0 - 1 + s;
        bool rev = (v < 0) || (v > 127);
        float a1A = rev ? y1_10 : y1_00, a2A = rev ? y2_10 : y2_00;
        float b1A = rev ? y1_00 : y1_10, b2A = rev ? y2_00 : y2_10;
        float a1B = rev ? y1_11 : y1_01, a2B = rev ? y2_11 : y2_01;
        float b1B = rev ? y1_01 : y1_11, b2B = rev ? y2_01 : y2_11;
        if (s == 0) {
            w1a[0]=a1A; w1a[1]=b1A; w2a[0]=a2A; w2a[1]=b2A;
            w1b[0]=a1B; w1b[1]=b1B; w2b[0]=a2B; w2b[1]=b2B;
        } else if (s == 1) {
            w1a[2]=a1A; w1a[3]=b1A; w2a[2]=a2A; w2a[3]=b2A;
            w1b[2]=a1B; w1b[3]=b1B; w2b[2]=a2B; w2b[3]=b2B;
        } else {
            const int r0 = i0 + 2 * (s - 2);
            float o0A = g0[0]*w1a[1] + g0[1]*w1a[2] + g0[2]*w1a[3]
                      + g1[0]*w2a[0] + g1[1]*w2a[1] + g1[2]*w2a[2]
                      + g1[3]*w2a[3] + g1[4]*a2A;
            float o1A = g0[0]*w1a[2] + g0[1]*w1a[3] + g0[2]*a1A
                      + g1[0]*w2a[1] + g1[1]*w2a[2] + g1[2]*w2a[3]
                      + g1[3]*a2A + g1[4]*b2A;
            float o0B = g0[0]*w1b[1] + g0[1]*w1b[2] + g0[2]*w1b[3]
                      + g1[0]*w2b[0] + g1[1]*w2b[1] + g1[2]*w2b[2]
                      + g1[3]*w2b[3] + g1[4]*a2B;
            float o1B = g0[0]*w1b[2] + g0[1]*w1b[3] + g0[2]*a1B
                      + g1[0]*w2b[1] + g1[1]*w2b[2] + g1[2]*w2b[3]
                      + g1[3]*a2B + g1[4]*b2B;
            ((float2*)outp)[r0 * 128 + c] = make_float2(o0A, o0B);
            ((float2*)outp)[(r0 + 1) * 128 + c] = make_float2(o1A, o1B);
            w1a[0]=w1a[2]; w1a[1]=w1a[3]; w1a[2]=a1A; w1a[3]=b1A;
            w2a[0]=w2a[2]; w2a[1]=w2a[3]; w2a[2]=a2A; w2a[3]=b2A;
            w1b[0]=w1b[2]; w1b[1]=w1b[3]; w1b[2]=a1B; w1b[3]=b1B;
            w2b[0]=w2b[2]; w2b[1]=w2b[3]; w2b[2]=a2B; w2b[3]=b2B;
        }
    };

    // ---- pipeline: issue-first counted-vmcnt ladder ----
    // Steady state: at WAIT(8), outstanding = 12 (stages s, s+1, s+2);
    // WAIT(8) drains exactly stage s's 4 loads. Ring-4 ensures issue(s+2)
    // never touches a buffer read later than compute(s-2) (2 barriers ago).
    issue(0); issue(1);
    for (int s = 0; s + 2 < NST; ++s) {
        issue(s + 2);
        WAIT(8); LGKM0(); BAR();
        computeStage(s);
    }
    WAIT(4); LGKM0(); BAR();
    computeStage(NST - 2);
    WAIT(0); LGKM0(); BAR();
    computeStage(NST - 1);
}

extern "C" void kernel_launch(void* const* d_in, const int* in_sizes, int n_in,
                              void* d_out, int out_size, void* d_ws, size_t ws_size,
                              hipStream_t stream) {
    const float* Yl  = (const float*)d_in[0];
    const float* Yhr = (const float*)d_in[1];
    const float* Yhi = (const float*)d_in[2];
    const float* g0o = (const float*)d_in[3];
    const float* g1o = (const float*)d_in[4];
    float* outp = (float*)d_out;
    dim3 grid(256, Hh / TH);   // 256 planes x 8 row tiles
    dim3 block(128);
    hipLaunchKernelGGL(dtcwt_inv, grid, block, 0, stream,
                       Yl, Yhr, Yhi, g0o, g1o, outp);
}

// Round 9
// 73.530 us; speedup vs baseline: 1.0989x; 1.0298x over previous
//
#include <hip/hip_runtime.h>

// Inverse DTCWT (biort legall) — single-wave blocks, zero barriers.
// Lane c (0..63) owns output cols 4c..4c+3. Subbands: 12 float2 reg-loads
// per stage (A/B banks, ~4-stage prefetch, compiler-exact waits). Yl:
// global_load_lds ring-3 + manual counted vmcnt (oldest-first-safe).
// c2q combined in-register, written once to LDS in a left-pad-2 layout so
// all compute reads are aligned conflict-free ds_read_b128.

#define Hh 256
#define Ww 256
#define W2 128
#define SBsz (128 * 128)
#define TH 32
#define NST 18            // row-pairs ip0-1 .. ip0+16 (clamped)
#define QS 260            // S row stride (words); S[w] = quad[w-2]
#define TSTR 264          // T row stride; T[w] = yl[w-4]
#define SOFF (2 * 6 * QS) // 3120
#define LDS_FLOATS (SOFF + 3 * 2 * TSTR)  // + T ring-3 = 4704 floats

#define WAIT(n) asm volatile("s_waitcnt vmcnt(" #n ")" ::: "memory")

struct Raw { float2 r1[3], r2[3], i1[3], i2[3]; };

__global__ __launch_bounds__(64) void dtcwt_inv(
    const float* __restrict__ Yl,
    const float* __restrict__ Yhr,
    const float* __restrict__ Yhi,
    const float* __restrict__ g0o,
    const float* __restrict__ g1o,
    float* __restrict__ out)
{
    const float SC = 0.70710678118654752440f;
    __shared__ __align__(16) float lds[LDS_FLOATS];

    const int c = threadIdx.x;            // 0..63
    const int plane = blockIdx.x;
    const int i0 = blockIdx.y * TH;
    const int ip0 = i0 >> 1;

    const float* yl  = Yl  + (size_t)plane * (Hh * Ww);
    const float* phr = Yhr + (size_t)plane * 6 * SBsz;
    const float* phi = Yhi + (size_t)plane * 6 * SBsz;
    float* outp = out + (size_t)plane * (Hh * Ww);

    float g0[3], g1[5], g0s[3], g1s[5];
#pragma unroll
    for (int t = 0; t < 3; ++t) { g0[t] = g0o[t]; g0s[t] = g0[t] * SC; }
#pragma unroll
    for (int t = 0; t < 5; ++t) { g1[t] = g1o[t]; g1s[t] = g1[t] * SC; }

    auto clampip = [&](int s) {
        int v = ip0 - 1 + s;
        return v < 0 ? 0 : (v > 127 ? 127 : v);
    };

    // 12 float2 register loads: pairs lh=(0,5), hl=(2,3), hh=(1,4).
    auto loadRaw = [&](int s, Raw& R) {
        if (s >= NST) return;
        const int off = clampip(s) * W2 + 2 * c;
        R.r1[0] = *(const float2*)(phr + 0 * SBsz + off);
        R.r2[0] = *(const float2*)(phr + 5 * SBsz + off);
        R.i1[0] = *(const float2*)(phi + 0 * SBsz + off);
        R.i2[0] = *(const float2*)(phi + 5 * SBsz + off);
        R.r1[1] = *(const float2*)(phr + 2 * SBsz + off);
        R.r2[1] = *(const float2*)(phr + 3 * SBsz + off);
        R.i1[1] = *(const float2*)(phi + 2 * SBsz + off);
        R.i2[1] = *(const float2*)(phi + 3 * SBsz + off);
        R.r1[2] = *(const float2*)(phr + 1 * SBsz + off);
        R.r2[2] = *(const float2*)(phr + 4 * SBsz + off);
        R.i1[2] = *(const float2*)(phi + 1 * SBsz + off);
        R.i2[2] = *(const float2*)(phi + 4 * SBsz + off);
    };

    // Yl rows 2ip,2ip+1 -> T slot s%3 via global_load_lds (linear dest +4 words).
    auto glYl = [&](int s) {
        if (s >= NST) return;
        const int ip = clampip(s);
        float* T = lds + SOFF + (s % 3) * 2 * TSTR;
#pragma unroll
        for (int r = 0; r < 2; ++r) {
            const float* src = yl + (size_t)(2 * ip + r) * Ww + 4 * c;
            __builtin_amdgcn_global_load_lds(
                (const __attribute__((address_space(1))) void*)src,
                (__attribute__((address_space(3))) void*)(T + r * TSTR + 4),
                16, 0, 0);
        }
    };

    // c2q combine in-register -> S slot s&1, left-pad-2 layout, float2 writes.
    auto writeS = [&](int s, const Raw& R) {
        if (s >= NST) return;
        float* S = lds + (s & 1) * 6 * QS;
#pragma unroll
        for (int p = 0; p < 3; ++p) {
            float2 r1 = R.r1[p], r2 = R.r2[p], i1 = R.i1[p], i2 = R.i2[p];
            float q00 = r1.x + r2.x, q01 = i1.x + i2.x;
            float q02 = r1.y + r2.y, q03 = i1.y + i2.y;
            float q10 = i1.x - i2.x, q11 = r2.x - r1.x;
            float q12 = i1.y - i2.y, q13 = r2.y - r1.y;
            float* S0 = S + (2 * p) * QS;
            float* S1 = S + (2 * p + 1) * QS;
            *(float2*)(S0 + 4 * c + 2) = make_float2(q00, q01);
            *(float2*)(S0 + 4 * c + 4) = make_float2(q02, q03);
            *(float2*)(S1 + 4 * c + 2) = make_float2(q10, q11);
            *(float2*)(S1 + 4 * c + 4) = make_float2(q12, q13);
            if (c == 0) {   // quad cols -2,-1 reflect -> 1,0
                *(float2*)S0 = make_float2(q01, q00);
                *(float2*)S1 = make_float2(q11, q10);
            }
            if (c == 63) {  // quad cols 256,257 reflect -> 255,254
                *(float2*)(S0 + 258) = make_float2(q03, q02);
                *(float2*)(S1 + 258) = make_float2(q13, q12);
            }
        }
    };

    float w1[4][4], w2[4][4];

    auto compute = [&](int s) {
        const float* S = lds + (s & 1) * 6 * QS;
        const float* T = lds + SOFF + (s % 3) * 2 * TSTR;
        float y10[4], y11[4], y20[4], y21[4];
        // ---- y1 = Yl(g0) + HL(g1s) ----
#pragma unroll
        for (int r = 0; r < 2; ++r) {
            const float* Tr = T + r * TSTR;
            float4 m  = *(const float4*)(Tr + 4 + 4 * c);
            float4 lf = *(const float4*)(Tr + (c == 0 ? 4 : 4 * c));
            float4 rf = *(const float4*)(Tr + (c == 63 ? 256 : 4 * c + 8));
            float ylw[6];
            ylw[0] = (c == 0) ? lf.x : lf.w;
            ylw[1] = m.x; ylw[2] = m.y; ylw[3] = m.z; ylw[4] = m.w;
            ylw[5] = (c == 63) ? rf.w : rf.x;
            float* yy = r ? y11 : y10;
#pragma unroll
            for (int dx = 0; dx < 4; ++dx)
                yy[dx] = g0[0] * ylw[dx] + g0[1] * ylw[dx + 1] + g0[2] * ylw[dx + 2];
        }
#pragma unroll
        for (int u = 0; u < 2; ++u) {
            const float* Hr = S + (2 + u) * QS;
            float4 a = *(const float4*)(Hr + 4 * c);
            float4 b = *(const float4*)(Hr + 4 * c + 4);
            float w[8] = {a.x, a.y, a.z, a.w, b.x, b.y, b.z, b.w};
            float* yy = u ? y11 : y10;
#pragma unroll
            for (int dx = 0; dx < 4; ++dx)
                yy[dx] += g1s[0] * w[dx] + g1s[1] * w[dx + 1] + g1s[2] * w[dx + 2]
                        + g1s[3] * w[dx + 3] + g1s[4] * w[dx + 4];
        }
        // ---- y2 = HH(g1s) + LH(g0s, offset +1) ----
#pragma unroll
        for (int u = 0; u < 2; ++u) {
            const float* Er = S + (4 + u) * QS;
            float4 a = *(const float4*)(Er + 4 * c);
            float4 b = *(const float4*)(Er + 4 * c + 4);
            float w[8] = {a.x, a.y, a.z, a.w, b.x, b.y, b.z, b.w};
            float* yy = u ? y21 : y20;
#pragma unroll
            for (int dx = 0; dx < 4; ++dx)
                yy[dx] = g1s[0] * w[dx] + g1s[1] * w[dx + 1] + g1s[2] * w[dx + 2]
                       + g1s[3] * w[dx + 3] + g1s[4] * w[dx + 4];
        }
#pragma unroll
        for (int u = 0; u < 2; ++u) {
            const float* Lr = S + u * QS;
            float4 a = *(const float4*)(Lr + 4 * c);
            float4 b = *(const float4*)(Lr + 4 * c + 4);
            float w[8] = {a.x, a.y, a.z, a.w, b.x, b.y, b.z, b.w};
            float* yy = u ? y21 : y20;
#pragma unroll
            for (int dx = 0; dx < 4; ++dx)
                yy[dx] += g0s[0] * w[dx + 1] + g0s[1] * w[dx + 2] + g0s[2] * w[dx + 3];
        }
        // ---- vertical reflection + column-filter sliding window ----
        int v = ip0 - 1 + s;
        bool rev = (v < 0) || (v > 127);
        float o0[4], o1[4];
#pragma unroll
        for (int dx = 0; dx < 4; ++dx) {
            float A1 = rev ? y11[dx] : y10[dx];
            float B1 = rev ? y10[dx] : y11[dx];
            float A2 = rev ? y21[dx] : y20[dx];
            float B2 = rev ? y20[dx] : y21[dx];
            if (s == 0) {
                w1[dx][0] = A1; w1[dx][1] = B1; w2[dx][0] = A2; w2[dx][1] = B2;
            } else if (s == 1) {
                w1[dx][2] = A1; w1[dx][3] = B1; w2[dx][2] = A2; w2[dx][3] = B2;
            } else {
                o0[dx] = g0[0]*w1[dx][1] + g0[1]*w1[dx][2] + g0[2]*w1[dx][3]
                       + g1[0]*w2[dx][0] + g1[1]*w2[dx][1] + g1[2]*w2[dx][2]
                       + g1[3]*w2[dx][3] + g1[4]*A2;
                o1[dx] = g0[0]*w1[dx][2] + g0[1]*w1[dx][3] + g0[2]*A1
                       + g1[0]*w2[dx][1] + g1[1]*w2[dx][2] + g1[2]*w2[dx][3]
                       + g1[3]*A2 + g1[4]*B2;
                w1[dx][0]=w1[dx][2]; w1[dx][1]=w1[dx][3]; w1[dx][2]=A1; w1[dx][3]=B1;
                w2[dx][0]=w2[dx][2]; w2[dx][1]=w2[dx][3]; w2[dx][2]=A2; w2[dx][3]=B2;
            }
        }
        if (s >= 2) {
            const int r0 = i0 + 2 * (s - 2);
            *(float4*)(outp + (size_t)r0 * Ww + 4 * c) =
                make_float4(o0[0], o0[1], o0[2], o0[3]);
            *(float4*)(outp + (size_t)(r0 + 1) * Ww + 4 * c) =
                make_float4(o1[0], o1[1], o1[2], o1[3]);
        }
    };

    Raw RA, RB;
    // ---- prologue ----
    loadRaw(0, RA); glYl(0);
    loadRaw(1, RB); glYl(1);
    writeS(0, RA);            // compiler waits raw0
    loadRaw(2, RA); glYl(2);
    writeS(1, RB);            // compiler waits raw1 (drains gl0 too)
    loadRaw(3, RB);

    // ---- steady loop: stages i, i+1 per body ----
    for (int i = 0; i <= 12; i += 2) {
        WAIT(26);                               // retire gl(i) (oldest-first safe)
        compute(i);
        __builtin_amdgcn_sched_barrier(0);
        glYl(i + 2);
        writeS(i + 2, RA);                      // compiler waits raw(i+2)
        loadRaw(i + 4, RA);
        WAIT(26);                               // retire gl(i+1)
        compute(i + 1);
        __builtin_amdgcn_sched_barrier(0);
        glYl(i + 3);
        writeS(i + 3, RB);                      // compiler waits raw(i+3)
        loadRaw(i + 5, RB);
    }
    // ---- peeled tail (tight counts) ----
    WAIT(26); compute(14);
    __builtin_amdgcn_sched_barrier(0);
    glYl(16); writeS(16, RA);
    WAIT(14); compute(15);
    __builtin_amdgcn_sched_barrier(0);
    glYl(17); writeS(17, RB);
    WAIT(2);  compute(16);
    WAIT(0);  compute(17);
}

extern "C" void kernel_launch(void* const* d_in, const int* in_sizes, int n_in,
                              void* d_out, int out_size, void* d_ws, size_t ws_size,
                              hipStream_t stream) {
    const float* Yl  = (const float*)d_in[0];
    const float* Yhr = (const float*)d_in[1];
    const float* Yhi = (const float*)d_in[2];
    const float* g0o = (const float*)d_in[3];
    const float* g1o = (const float*)d_in[4];
    float* outp = (float*)d_out;
    dim3 grid(256, Hh / TH);   // 256 planes x 8 row tiles, 1 wave/block
    dim3 block(64);
    hipLaunchKernelGGL(dtcwt_inv, grid, block, 0, stream,
                       Yl, Yhr, Yhi, g0o, g1o, outp);
}